// Round 1
// 243.043 us; speedup vs baseline: 1.0897x; 1.0897x over previous
//
#include <hip/hip_runtime.h>

#define D 128
#define BN_EPS 1e-5f
#define CHUNK 2048           // edges per scatter block (256 thr x 8)
#define CAP 6144             // padded bucket capacity (mean 4096, +32 sigma)
#define AST 136              // bf16 LDS row stride (128+8, keeps 16B alignment)

typedef __attribute__((ext_vector_type(8))) short bf16x8;
typedef __attribute__((ext_vector_type(4))) float f32x4;

// RNE round f32 -> bf16
__device__ __forceinline__ unsigned short bf16r(float a) {
    unsigned u = __float_as_uint(a);
    u += 0x7fff + ((u >> 16) & 1);
    return (unsigned short)(u >> 16);
}
__device__ __forceinline__ unsigned bf16pairp(float a, float b) {
    return (unsigned)bf16r(a) | ((unsigned)bf16r(b) << 16);
}

// ---------------- shared GEMM tile body ----------------
// Yb[64 rows @ row0] = bf16( f(X) @ W ), W is f32 row-major [k][c].
// f = identity when sums==null, else relu(x*scale+shift) with BN scale/shift
// computed in-block from sums/gamma/beta (replaces the finalize kernel).
// B staged by in-block transpose: 4 coalesced dword loads down column c,
// one 8B LDS write of a k-run of 4 bf16.
__device__ __forceinline__ void gemm_tile(int bid, const float* __restrict__ X,
                                          const float* __restrict__ W,
                                          const float* __restrict__ sums,
                                          const float* __restrict__ gamma,
                                          const float* __restrict__ beta,
                                          unsigned short* __restrict__ Yb, int n,
                                          unsigned short* Abf, unsigned short* Bbf,
                                          float* scsh, int tid) {
    int row0 = bid * 64;
#pragma unroll
    for (int p = 0; p < 16; p++) {
        int idx = tid + p * 256;            // 0..4095
        int c = idx & 127, k0 = (idx >> 7) * 4;
        float w0 = W[(size_t)(k0 + 0) * D + c];
        float w1 = W[(size_t)(k0 + 1) * D + c];
        float w2 = W[(size_t)(k0 + 2) * D + c];
        float w3 = W[(size_t)(k0 + 3) * D + c];
        uint2 pk;
        pk.x = bf16pairp(w0, w1);
        pk.y = bf16pairp(w2, w3);
        *(uint2*)&Bbf[c * AST + k0] = pk;   // (c*272 + 2*k0) is 8B aligned
    }
    bool bn = (sums != nullptr);
    if (bn) {
        if (tid < D) {
            float inv_n = 1.0f / (float)n;
            float mu = sums[tid] * inv_n;
            float var = sums[D + tid] * inv_n - mu * mu;
            float is = rsqrtf(var + BN_EPS);
            float scl = gamma[tid] * is;
            scsh[tid] = scl;
            scsh[D + tid] = beta[tid] - mu * scl;
        }
        __syncthreads();                    // scsh visible before A-stage
    }
    // stage f(X) -> Abf bf16: 64 rows x 32 float4 (4 cols each)
#pragma unroll
    for (int p = 0; p < 8; p++) {
        int idx = tid + p * 256;
        int r = idx >> 5, k4 = idx & 31;
        int grow = row0 + r;
        float4 v = make_float4(0.f, 0.f, 0.f, 0.f);
        if (grow < n) v = *(const float4*)(X + (size_t)grow * D + k4 * 4);
        if (bn) {
            float4 scl = ((const float4*)scsh)[k4];
            float4 sh  = ((const float4*)(scsh + D))[k4];
            v.x = fmaxf(fmaf(v.x, scl.x, sh.x), 0.f);
            v.y = fmaxf(fmaf(v.y, scl.y, sh.y), 0.f);
            v.z = fmaxf(fmaf(v.z, scl.z, sh.z), 0.f);
            v.w = fmaxf(fmaf(v.w, scl.w, sh.w), 0.f);
        }
        uint2 pk;
        pk.x = bf16pairp(v.x, v.y);
        pk.y = bf16pairp(v.z, v.w);
        *(uint2*)&Abf[r * AST + k4 * 4] = pk;
    }
    __syncthreads();

    int w = tid >> 6, lane = tid & 63;
    int m = lane & 15, quad = lane >> 4;

    bf16x8 av[4];
#pragma unroll
    for (int ks = 0; ks < 4; ks++)
        av[ks] = *(const bf16x8*)&Abf[(w * 16 + m) * AST + ks * 32 + quad * 8];

    f32x4 acc[8];
#pragma unroll
    for (int ct = 0; ct < 8; ct++) acc[ct] = (f32x4){0.f, 0.f, 0.f, 0.f};

#pragma unroll
    for (int ct = 0; ct < 8; ct++) {
#pragma unroll
        for (int ks = 0; ks < 4; ks++) {
            bf16x8 bv = *(const bf16x8*)&Bbf[(ct * 16 + m) * AST + ks * 32 + quad * 8];
            acc[ct] = __builtin_amdgcn_mfma_f32_16x16x32_bf16(av[ks], bv, acc[ct], 0, 0, 0);
        }
    }

    int rb = row0 + w * 16 + quad * 4;
#pragma unroll
    for (int ct = 0; ct < 8; ct++) {
#pragma unroll
        for (int r = 0; r < 4; r++) {
            int grow = rb + r;
            if (grow < n)
                Yb[(size_t)grow * D + ct * 16 + m] = bf16r(acc[ct][r]);
        }
    }
}

// ---------------- fused kernel 1: bucket scatter || GEMM1 ----------------
// blocks [0,nchunks): scatter (src,dst) pairs into padded buckets (base=b*CAP,
// global cursors pre-zeroed). blocks [nchunks,..): GEMM1 tiles (independent:
// payload is UNSCALED, dinv is applied per-edge in aggregation).
__global__ __launch_bounds__(256) void k_fuse1(const int* __restrict__ src,
                                               const int* __restrict__ dst,
                                               int* __restrict__ bcur,
                                               int2* __restrict__ bpairs,
                                               int E, int nb, int nchunks,
                                               const float* __restrict__ X,
                                               const float* __restrict__ W1,
                                               unsigned short* __restrict__ Yb, int n) {
    __shared__ unsigned short Abf[64 * AST];
    __shared__ unsigned short Bbf[128 * AST];
    __shared__ int h[256];
    int tid = threadIdx.x;
    if (blockIdx.x >= nchunks) {
        gemm_tile(blockIdx.x - nchunks, X, W1, nullptr, nullptr, nullptr,
                  Yb, n, Abf, Bbf, nullptr, tid);
        return;
    }
    h[tid] = 0;
    __syncthreads();
    int base = blockIdx.x * CHUNK + tid;
    int s[8], t[8], r[8];
#pragma unroll
    for (int k = 0; k < 8; k++) {
        int i = base + k * 256;
        if (i < E) {
            s[k] = src[i];
            t[k] = dst[i];
            r[k] = atomicAdd(&h[t[k] >> 8], 1);
        } else {
            t[k] = -1;
        }
    }
    __syncthreads();
    if (tid < nb) {
        int c = h[tid];
        h[tid] = c ? atomicAdd(&bcur[tid], c) : 0;
    }
    __syncthreads();
#pragma unroll
    for (int k = 0; k < 8; k++) {
        if (t[k] >= 0) {
            int b = t[k] >> 8;
            int pos = h[b] + r[k];
            if (pos < CAP) bpairs[(size_t)b * CAP + pos] = make_int2(s[k], t[k]);
        }
    }
}

// ---------------- per-bucket CSR finalize (rowptr, rowcnt, dinv, csr) -------
__global__ __launch_bounds__(256) void k_csr(const int2* __restrict__ bpairs,
                                             const int* __restrict__ bcnt,
                                             int* __restrict__ rowptr,
                                             int* __restrict__ rowcnt,
                                             int* __restrict__ csr,
                                             float* __restrict__ dinv, int n) {
    int b = blockIdx.x;
    int tid = threadIdx.x;
    size_t lo = (size_t)b * CAP;
    int cnt = bcnt[b];
    if (cnt > CAP) cnt = CAP;
    __shared__ int h[256];
    __shared__ int sh[256];
    h[tid] = 0;
    __syncthreads();
    for (int i = tid; i < cnt; i += 256) atomicAdd(&h[bpairs[lo + i].y & 255], 1);
    __syncthreads();
    int c = h[tid];
    sh[tid] = c;
    __syncthreads();
    for (int off = 1; off < 256; off <<= 1) {
        int u = (tid >= off) ? sh[tid - off] : 0;
        __syncthreads();
        sh[tid] += u;
        __syncthreads();
    }
    int ex = sh[tid] - c;
    int row = b * 256 + tid;
    if (row < n) {
        rowptr[row] = (int)lo + ex;
        rowcnt[row] = c;
        dinv[row] = rsqrtf((float)(c + 1));   // +1 = self loop
    }
    __syncthreads();
    h[tid] = (int)lo + ex;                    // reuse as cursor
    __syncthreads();
    for (int i = tid; i < cnt; i += 256) {
        int2 p = bpairs[lo + i];
        int pos = atomicAdd(&h[p.y & 255], 1);
        csr[pos] = p.x;
    }
}

// ---------------- slot-gather aggregation, per-edge dinv weighting ---------
// OUT[t] = ( dinv[t]*Hb[t] + sum_{s in N(t)} dinv[s]*Hb[s] ) * dinv[t] + bias
__device__ __forceinline__ void unpack_fma(uint4 u, float d, float* acc) {
    acc[0] = fmaf(d, __uint_as_float(u.x << 16), acc[0]);
    acc[1] = fmaf(d, __uint_as_float(u.x & 0xffff0000u), acc[1]);
    acc[2] = fmaf(d, __uint_as_float(u.y << 16), acc[2]);
    acc[3] = fmaf(d, __uint_as_float(u.y & 0xffff0000u), acc[3]);
    acc[4] = fmaf(d, __uint_as_float(u.z << 16), acc[4]);
    acc[5] = fmaf(d, __uint_as_float(u.z & 0xffff0000u), acc[5]);
    acc[6] = fmaf(d, __uint_as_float(u.w << 16), acc[6]);
    acc[7] = fmaf(d, __uint_as_float(u.w & 0xffff0000u), acc[7]);
}

__global__ __launch_bounds__(256) void k_agg(const unsigned short* __restrict__ Hb,
                                             const int* __restrict__ csr_src,
                                             const int* __restrict__ rowptr,
                                             const int* __restrict__ rowcnt,
                                             const float* __restrict__ dinv,
                                             const float* __restrict__ bias,
                                             float* __restrict__ OUT, int n) {
    int row = blockIdx.x * 4 + (threadIdx.x >> 6);
    if (row >= n) return;
    int lane = threadIdx.x & 63;
    int slot = lane >> 4, seg = lane & 15;
    const uint4* HB4 = (const uint4*)Hb;
    float dt = dinv[row];

    float acc[8];
#pragma unroll
    for (int i = 0; i < 8; i++) acc[i] = 0.f;
    if (slot == 0) {                       // self term, weight dinv[row]
        uint4 us = HB4[(size_t)row * 16 + seg];
        unpack_fma(us, dt, acc);
    }

    int k0 = rowptr[row];
    int deg = rowcnt[row];
    int iters = deg >> 2;
    int k = k0 + slot;
    int it = 0;
    for (; it + 4 <= iters; it += 4, k += 16) {
        int s0 = csr_src[k], s1 = csr_src[k + 4];
        int s2 = csr_src[k + 8], s3 = csr_src[k + 12];
        float d0 = dinv[s0], d1 = dinv[s1], d2 = dinv[s2], d3 = dinv[s3];
        uint4 u0 = HB4[(size_t)s0 * 16 + seg];
        uint4 u1 = HB4[(size_t)s1 * 16 + seg];
        uint4 u2 = HB4[(size_t)s2 * 16 + seg];
        uint4 u3 = HB4[(size_t)s3 * 16 + seg];
        unpack_fma(u0, d0, acc);
        unpack_fma(u1, d1, acc);
        unpack_fma(u2, d2, acc);
        unpack_fma(u3, d3, acc);
    }
    for (; it < iters; it++, k += 4) {
        int s = csr_src[k];
        float d = dinv[s];
        uint4 u = HB4[(size_t)s * 16 + seg];
        unpack_fma(u, d, acc);
    }
    if (slot < (deg & 3)) {                // tail edges
        int s = csr_src[k];
        float d = dinv[s];
        uint4 u = HB4[(size_t)s * 16 + seg];
        unpack_fma(u, d, acc);
    }

#pragma unroll
    for (int i = 0; i < 8; i++) {
        acc[i] += __shfl_xor(acc[i], 16, 64);
        acc[i] += __shfl_xor(acc[i], 32, 64);
    }

    float v0 = acc[slot * 2] * dt;
    float v1 = acc[slot * 2 + 1] * dt;
    int cp = seg * 4 + slot;               // float2 index = col/2
    if (bias) {
        float2 b = ((const float2*)bias)[cp];
        v0 += b.x;
        v1 += b.y;
    }
    ((float2*)OUT)[(size_t)row * 64 + cp] = make_float2(v0, v1);
}

// ---------------- BN stats (512-way atomic contention, safe) ----------------
__global__ __launch_bounds__(128) void k_bn_stats(const float* __restrict__ A,
                                                  float* __restrict__ sums, int n) {
    int j = threadIdx.x;
    float s = 0.f, ss = 0.f;
    for (int r = blockIdx.x; r < n; r += gridDim.x) {
        float v = A[(size_t)r * D + j];
        s += v;
        ss += v * v;
    }
    atomicAdd(&sums[j], s);
    atomicAdd(&sums[D + j], ss);
}

// ---------------- GEMM2 with fused BN finalize + relu ----------------
__global__ __launch_bounds__(256) void k_gemm2(const float* __restrict__ X,
                                               const float* __restrict__ W,
                                               const float* __restrict__ sums,
                                               const float* __restrict__ gamma,
                                               const float* __restrict__ beta,
                                               unsigned short* __restrict__ Yb, int n) {
    __shared__ unsigned short Abf[64 * AST];
    __shared__ unsigned short Bbf[128 * AST];
    __shared__ float scsh[256];
    gemm_tile(blockIdx.x, X, W, sums, gamma, beta, Yb, n, Abf, Bbf, scsh, threadIdx.x);
}

extern "C" void kernel_launch(void* const* d_in, const int* in_sizes, int n_in,
                              void* d_out, int out_size, void* d_ws, size_t ws_size,
                              hipStream_t stream) {
    const float* x     = (const float*)d_in[0];
    const int*   ei    = (const int*)d_in[1];
    const float* W1    = (const float*)d_in[2];
    // d_in[3] = b1 — cancels exactly in BatchNorm, unused
    const float* gamma = (const float*)d_in[4];
    const float* beta  = (const float*)d_in[5];
    const float* W2    = (const float*)d_in[6];
    const float* b2    = (const float*)d_in[7];
    float* out = (float*)d_out;

    int n = in_sizes[0] / D;   // 50000
    int E = in_sizes[1] / 2;   // 800000
    const int* src = ei;
    const int* dst = ei + E;
    int nb = (n + 255) >> 8;          // 196 buckets (<= 256)
    int nchunks = (E + CHUNK - 1) / CHUNK;
    int gblocks = (n + 63) / 64;

    char* ws = (char*)d_ws;
    size_t off = 0;
    auto alloc = [&](size_t bytes) {
        char* p = ws + off;
        off = (off + bytes + 511) & ~(size_t)511;
        return p;
    };
    float*          agg    = (float*)alloc((size_t)n * D * sizeof(float));
    unsigned short* hbf    = (unsigned short*)alloc((size_t)n * D * 2);
    float*          dinv   = (float*)alloc(n * sizeof(float));
    int*            rowptr = (int*)alloc(n * sizeof(int));
    int*            rowcnt = (int*)alloc(n * sizeof(int));
    int*            bcur   = (int*)alloc(512 * sizeof(int));   // bcur[256] + sums[256]
    float*          sums   = (float*)(bcur + 256);
    int2*           bpairs = (int2*)alloc((size_t)nb * CAP * sizeof(int2));
    int*            csr    = (int*)alloc((size_t)nb * CAP * sizeof(int));

    // zero bucket cursors + BN sums in one fill (contiguous 2KB)
    hipMemsetAsync(bcur, 0, 512 * sizeof(int), stream);

    // scatter || GEMM1 (payload unscaled; dinv applied per-edge in agg)
    k_fuse1<<<nchunks + gblocks, 256, 0, stream>>>(src, dst, bcur, bpairs, E, nb,
                                                   nchunks, x, W1, hbf, n);
    k_csr<<<nb, 256, 0, stream>>>(bpairs, bcur, rowptr, rowcnt, csr, dinv, n);

    // conv1 aggregate -> agg (f32, BN input)
    k_agg<<<(n + 3) / 4, 256, 0, stream>>>(hbf, csr, rowptr, rowcnt, dinv,
                                           nullptr, agg, n);
    // BN stats
    k_bn_stats<<<512, 128, 0, stream>>>(agg, sums, n);

    // conv2: hbf = bf16(relu(BN(agg)) @ W2)  (finalize fused in-block)
    k_gemm2<<<gblocks, 256, 0, stream>>>(agg, W2, sums, gamma, beta, hbf, n);
    // conv2 aggregate + b2 -> out
    k_agg<<<(n + 3) / 4, 256, 0, stream>>>(hbf, csr, rowptr, rowcnt, dinv,
                                           b2, out, n);
}